// Round 9
// baseline (613.692 us; speedup 1.0000x reference)
//
#include <hip/hip_runtime.h>
#include <cmath>

#define Tseq 2048
#define Dm   1024
#define NHd  16
#define HDim 64
#define Mrows 4096   // B*T = 2*2048
#define QS   3072    // packed QKV row stride (f16 elems)
#define PAD  72      // LDS row stride (f16) for attention tiles
#define NSPLIT 16    // j-splits for the global row (i = T-1)

typedef _Float16 f16;
typedef _Float16 half8 __attribute__((ext_vector_type(8)));
typedef _Float16 half4 __attribute__((ext_vector_type(4)));
typedef float    floatx4 __attribute__((ext_vector_type(4)));

#define ASYNC_COPY16(g, l)                                                       \
  __builtin_amdgcn_global_load_lds((const __attribute__((address_space(1))) void*)(g), \
                                   (__attribute__((address_space(3))) void*)(l), 16, 0, 0)

// tanh-form GELU, one __expf. |err vs exact erf-GELU| <= ~3e-4.
__device__ __forceinline__ float gelu_f(float v) {
  const float u = 0.7978845608028654f * (v + 0.044715f * v * v * v);
  const float e = __expf(2.0f * u);
  return 0.5f * v * (2.0f - 2.0f / (e + 1.0f));
}

// ---------------------------------------------------------------- transpose + cast
__global__ __launch_bounds__(256) void transp_f16(const float* __restrict__ W,
                                                  f16* __restrict__ Wt, int K, int N) {
  __shared__ float tile[32][33];
  const int n0 = blockIdx.x * 32, k0 = blockIdx.y * 32;
  const int tx = threadIdx.x & 31, ty = threadIdx.x >> 5;
#pragma unroll
  for (int i = 0; i < 32; i += 8)
    tile[ty + i][tx] = W[(size_t)(k0 + ty + i) * N + n0 + tx];
  __syncthreads();
#pragma unroll
  for (int i = 0; i < 32; i += 8)
    Wt[(size_t)(n0 + ty + i) * K + k0 + tx] = (f16)tile[tx][ty + i];
}

// Q/K/V transposes in one launch (blockIdx.z selects the weight)
__global__ __launch_bounds__(256) void transp_qkv(const float* __restrict__ Wq,
                                                  const float* __restrict__ Wk,
                                                  const float* __restrict__ Wv,
                                                  f16* __restrict__ Wt) {
  __shared__ float tile[32][33];
  const float* W = (blockIdx.z == 0) ? Wq : (blockIdx.z == 1) ? Wk : Wv;
  f16* dst = Wt + (size_t)blockIdx.z * Dm * Dm;
  const int n0 = blockIdx.x * 32, k0 = blockIdx.y * 32;
  const int tx = threadIdx.x & 31, ty = threadIdx.x >> 5;
#pragma unroll
  for (int i = 0; i < 32; i += 8)
    tile[ty + i][tx] = W[(size_t)(k0 + ty + i) * Dm + n0 + tx];
  __syncthreads();
#pragma unroll
  for (int i = 0; i < 32; i += 8)
    dst[(size_t)(n0 + ty + i) * Dm + k0 + tx] = (f16)tile[tx][ty + i];
}

// ---------------------------------------------------------------- layernorm -> f16
__global__ __launch_bounds__(256) void ln_f16(const float* __restrict__ x,
                                              const float* __restrict__ g,
                                              const float* __restrict__ bb,
                                              f16* __restrict__ out) {
  const int row = blockIdx.x, t = threadIdx.x;
  const float4 v = ((const float4*)(x + (size_t)row * Dm))[t];
  float s  = v.x + v.y + v.z + v.w;
  float ss = v.x * v.x + v.y * v.y + v.z * v.z + v.w * v.w;
#pragma unroll
  for (int m = 32; m >= 1; m >>= 1) { s += __shfl_xor(s, m); ss += __shfl_xor(ss, m); }
  __shared__ float red[8];
  if ((t & 63) == 0) { red[t >> 6] = s; red[4 + (t >> 6)] = ss; }
  __syncthreads();
  const float S  = red[0] + red[1] + red[2] + red[3];
  const float SS = red[4] + red[5] + red[6] + red[7];
  const float mean = S * (1.0f / Dm);
  const float inv  = rsqrtf(SS * (1.0f / Dm) - mean * mean + 1e-5f);
  const float4 gg = ((const float4*)g)[t];
  const float4 bv = ((const float4*)bb)[t];
  half4 o;
  o.x = (f16)(((v.x - mean) * inv) * gg.x + bv.x);
  o.y = (f16)(((v.y - mean) * inv) * gg.y + bv.y);
  o.z = (f16)(((v.z - mean) * inv) * gg.z + bv.z);
  o.w = (f16)(((v.w - mean) * inv) * gg.w + bv.w);
  *((half4*)(out + (size_t)row * Dm) + t) = o;
}

// ---------------------------------------------------------------- split-K reduce (+ fused LN)
template <int NS>
__global__ __launch_bounds__(256) void reduce_ln(const f16* __restrict__ P,
                                                 const float* __restrict__ resid,
                                                 const float* __restrict__ bias,
                                                 const float* __restrict__ g,
                                                 const float* __restrict__ bb,
                                                 float* __restrict__ x1,
                                                 f16* __restrict__ h) {
  const int row = blockIdx.x, t = threadIdx.x;
  const size_t idx = (size_t)row * (Dm / 4) + t;
  const float4 r = ((const float4*)resid)[idx];
  const float4 b = ((const float4*)bias)[t];
  float4 o; o.x = r.x + b.x; o.y = r.y + b.y; o.z = r.z + b.z; o.w = r.w + b.w;
#pragma unroll
  for (int z = 0; z < NS; ++z) {
    const half4 p = ((const half4*)(P + (size_t)z * Mrows * Dm))[idx];
    o.x += (float)p[0]; o.y += (float)p[1]; o.z += (float)p[2]; o.w += (float)p[3];
  }
  ((float4*)x1)[idx] = o;
  float s  = o.x + o.y + o.z + o.w;
  float ss = o.x * o.x + o.y * o.y + o.z * o.z + o.w * o.w;
#pragma unroll
  for (int m = 32; m >= 1; m >>= 1) { s += __shfl_xor(s, m); ss += __shfl_xor(ss, m); }
  __shared__ float red[8];
  if ((t & 63) == 0) { red[t >> 6] = s; red[4 + (t >> 6)] = ss; }
  __syncthreads();
  const float S  = red[0] + red[1] + red[2] + red[3];
  const float SS = red[4] + red[5] + red[6] + red[7];
  const float mean = S * (1.0f / Dm);
  const float inv  = rsqrtf(SS * (1.0f / Dm) - mean * mean + 1e-5f);
  const float4 gg = ((const float4*)g)[t];
  const float4 bv = ((const float4*)bb)[t];
  half4 oh;
  oh[0] = (f16)(((o.x - mean) * inv) * gg.x + bv.x);
  oh[1] = (f16)(((o.y - mean) * inv) * gg.y + bv.y);
  oh[2] = (f16)(((o.z - mean) * inv) * gg.z + bv.z);
  oh[3] = (f16)(((o.w - mean) * inv) * gg.w + bv.w);
  ((half4*)h)[idx] = oh;
}

// ---------------------------------------------------------------- GEMM 128x128, BK=64 (f16 MFMA)
// EPI 2: gelu(C+bias)->f16.  EPI 3: C->f16.
// EPI 5: f16 partial slab (split-K, flat grid, z in low bits for XCD spread).
// EPI 6: EPI5 + last-finisher reduces all NZ slabs + bias + resid -> fp32 out.
// LNZ = log2(#K-chunks). Flat-grid decode for EPI>=5: z=lin&(NZ-1), n=(lin>>LNZ)&7, m=rest.
template <int EPI, int LNZ>
__global__ __launch_bounds__(256, 4) void gemm_f16(const f16* __restrict__ A,
                                                   const f16* __restrict__ Bt,
                                                   int M, int N, int K, int kLen,
                                                   const float* __restrict__ bias,
                                                   f16* __restrict__ Ch,
                                                   const float* __restrict__ resid,
                                                   float* __restrict__ Cf,
                                                   int* __restrict__ cnt) {
  constexpr int NZ = 1 << LNZ;
  __shared__ f16 As[128 * 64];   // 16 KB
  __shared__ f16 Bs[128 * 64];   // 16 KB
  const int tid = threadIdx.x;
  int bx, by, bz;
  if (EPI >= 5) {
    const int lin = blockIdx.x;
    bz = lin & (NZ - 1);
    bx = (lin >> LNZ) & 7;        // N/128 == 8 for these GEMMs
    by = lin >> (LNZ + 3);
  } else {
    bx = blockIdx.x; by = blockIdx.y; bz = blockIdx.z;
  }
  const int m0 = by * 128, n0 = bx * 128;
  const int kOff = bz * kLen;
  const int w = tid >> 6, l = tid & 63;
  const int wr = (w >> 1) * 64, wc = (w & 1) * 64;
  const int c = l & 15, qq = l >> 4;
  const int cx = c & 7;            // swizzle key for fragment reads
  const int srow = tid >> 3;       // 0..31 (staging row within 32-row group)
  const int scol = ((tid & 7) ^ (srow & 7)) * 8;  // swizzled global col (f16)

  floatx4 acc[4][4] = {};

  const f16* Ab = A + (size_t)(m0 + srow) * K + kOff + scol;
  const f16* Bb = Bt + (size_t)(n0 + srow) * K + kOff + scol;

  for (int k0 = 0; k0 < kLen; k0 += 64) {
    __syncthreads();
#pragma unroll
    for (int i = 0; i < 4; ++i) {
      ASYNC_COPY16(Ab + k0 + (size_t)(i * 32) * K, As + i * 2048 + w * 512);
      ASYNC_COPY16(Bb + k0 + (size_t)(i * 32) * K, Bs + i * 2048 + w * 512);
    }
    __syncthreads();
    half8 af[4][2], bfr[4][2];
#pragma unroll
    for (int t = 0; t < 4; ++t) {
      const int ra = (wr + t * 16 + c) * 64;
      af[t][0] = *(const half8*)&As[ra + ((qq ^ cx) * 8)];
      af[t][1] = *(const half8*)&As[ra + (((4 + qq) ^ cx) * 8)];
      const int rb = (wc + t * 16 + c) * 64;
      bfr[t][0] = *(const half8*)&Bs[rb + ((qq ^ cx) * 8)];
      bfr[t][1] = *(const half8*)&Bs[rb + (((4 + qq) ^ cx) * 8)];
    }
#pragma unroll
    for (int ti = 0; ti < 4; ++ti)
#pragma unroll
      for (int tj = 0; tj < 4; ++tj) {
        acc[ti][tj] = __builtin_amdgcn_mfma_f32_16x16x32_f16(af[ti][0], bfr[tj][0], acc[ti][tj], 0, 0, 0);
        acc[ti][tj] = __builtin_amdgcn_mfma_f32_16x16x32_f16(af[ti][1], bfr[tj][1], acc[ti][tj], 0, 0, 0);
      }
  }

  f16* Cw = (EPI >= 5) ? (Ch + (size_t)bz * M * N) : Ch;
#pragma unroll
  for (int ti = 0; ti < 4; ++ti)
#pragma unroll
    for (int tj = 0; tj < 4; ++tj)
#pragma unroll
      for (int r = 0; r < 4; ++r) {
        const int row = m0 + wr + ti * 16 + qq * 4 + r;
        const int col = n0 + wc + tj * 16 + c;
        const size_t idx = (size_t)row * N + col;
        float v = acc[ti][tj][r];
        if (EPI == 2) {
          Cw[idx] = (f16)gelu_f(v + bias[col]);
        } else {
          Cw[idx] = (f16)v;
        }
      }

  if (EPI == 6) {
    // last z-block for this (m,n) tile reduces all NZ slabs -> fp32 out
    __shared__ int ticket;
    __threadfence();
    __syncthreads();
    if (tid == 0) ticket = atomicAdd(&cnt[by * 8 + bx], 1);
    __syncthreads();
    if (ticket == NZ - 1) {
      __threadfence();
      const int ncol4 = N >> 2;
      for (int e = tid; e < 128 * 32; e += 256) {   // 128 rows x 32 float4
        const int rr2 = e >> 5, c4 = e & 31;
        const size_t i4 = (size_t)(m0 + rr2) * ncol4 + (n0 >> 2) + c4;
        const float4 rv = ((const float4*)resid)[i4];
        const float4 bv = ((const float4*)bias)[(n0 >> 2) + c4];
        float4 o; o.x = rv.x + bv.x; o.y = rv.y + bv.y; o.z = rv.z + bv.z; o.w = rv.w + bv.w;
#pragma unroll
        for (int z = 0; z < NZ; ++z) {
          const half4 p = ((const half4*)(Ch + (size_t)z * M * N))[i4];
          o.x += (float)p[0]; o.y += (float)p[1]; o.z += (float)p[2]; o.w += (float)p[3];
        }
        ((float4*)Cf)[i4] = o;
      }
    }
  }
}

// ---------------------------------------------------------------- windowed attention (MFMA)
__global__ __launch_bounds__(256, 4) void attn_win(const f16* __restrict__ qkv,
                                                   f16* __restrict__ ao) {
  __shared__ f16 qs[64 * PAD];   // [i][d]
  __shared__ f16 ks[64 * PAD];   // [j][d]
  __shared__ f16 vts[64 * PAD];  // [d][j]  (transposed)
  __shared__ f16 ps[64 * PAD];   // [i][j]  wave-private row slices
  const int qt = blockIdx.x;
  const int b = blockIdx.y >> 4, hh = blockIdx.y & 15;
  const int q0 = qt * 64;
  const int tid = threadIdx.x, w = tid >> 6, l = tid & 63;
  const int c = l & 15, qq = l >> 4;
  const int wr = w * 16;
  const size_t base = ((size_t)b * Tseq) * QS + hh * HDim;
  const int rr = tid >> 2, ss = (tid & 3) * 16;

  {
    const f16* src = qkv + base + (size_t)(q0 + rr) * QS + ss;
    *(uint4*)&qs[rr * PAD + ss]     = *(const uint4*)src;
    *(uint4*)&qs[rr * PAD + ss + 8] = *(const uint4*)(src + 8);
  }

  float m_run[4], l_run[4];
  floatx4 oacc[4];
#pragma unroll
  for (int r = 0; r < 4; ++r) { m_run[r] = -INFINITY; l_run[r] = 0.f; }
#pragma unroll
  for (int td = 0; td < 4; ++td) oacc[td] = (floatx4){0.f, 0.f, 0.f, 0.f};

  int chunks[4]; int nch = 0;
  if (qt > 2) chunks[nch++] = 0;
  for (int ch = (qt - 2 > 0 ? qt - 2 : 0); ch <= qt; ++ch) chunks[nch++] = ch;

  for (int ci = 0; ci < nch; ++ci) {
    const int j0 = chunks[ci] * 64;
    __syncthreads();
    {
      const f16* srck = qkv + base + 1024 + (size_t)(j0 + rr) * QS + ss;
      *(uint4*)&ks[rr * PAD + ss]     = *(const uint4*)srck;
      *(uint4*)&ks[rr * PAD + ss + 8] = *(const uint4*)(srck + 8);
      const f16* srcv = qkv + base + 2048 + (size_t)(j0 + rr) * QS + ss;
      uint4 va0 = *(const uint4*)srcv;
      uint4 va1 = *(const uint4*)(srcv + 8);
      const f16* e0 = (const f16*)&va0;
      const f16* e1 = (const f16*)&va1;
#pragma unroll
      for (int i = 0; i < 8; ++i) vts[(ss + i) * PAD + rr] = e0[i];
#pragma unroll
      for (int i = 0; i < 8; ++i) vts[(ss + 8 + i) * PAD + rr] = e1[i];
    }
    __syncthreads();

    const half8 a0 = *(const half8*)&qs[(wr + c) * PAD + qq * 8];
    const half8 a1 = *(const half8*)&qs[(wr + c) * PAD + 32 + qq * 8];
    floatx4 sacc[4];
#pragma unroll
    for (int tj = 0; tj < 4; ++tj) {
      const half8 b0 = *(const half8*)&ks[(tj * 16 + c) * PAD + qq * 8];
      const half8 b1 = *(const half8*)&ks[(tj * 16 + c) * PAD + 32 + qq * 8];
      floatx4 s4 = {0.f, 0.f, 0.f, 0.f};
      s4 = __builtin_amdgcn_mfma_f32_16x16x32_f16(a0, b0, s4, 0, 0, 0);
      s4 = __builtin_amdgcn_mfma_f32_16x16x32_f16(a1, b1, s4, 0, 0, 0);
      sacc[tj] = s4;
    }

#pragma unroll
    for (int r = 0; r < 4; ++r) {
      const int ii = q0 + wr + qq * 4 + r;
      float sv[4];
      float mx = -INFINITY;
#pragma unroll
      for (int tj = 0; tj < 4; ++tj) {
        const int jj = j0 + tj * 16 + c;
        const bool allowed = (jj <= ii) && ((ii - jj) <= 128 || jj == 0);
        sv[tj] = allowed ? sacc[tj][r] * 0.125f : -INFINITY;
        mx = fmaxf(mx, sv[tj]);
      }
#pragma unroll
      for (int mm = 8; mm >= 1; mm >>= 1) mx = fmaxf(mx, __shfl_xor(mx, mm));
      const float mn = fmaxf(m_run[r], mx);
      const float alpha = (mn == -INFINITY) ? 1.f : __expf(m_run[r] - mn);
      float sum = 0.f;
      float p[4];
#pragma unroll
      for (int tj = 0; tj < 4; ++tj) { p[tj] = __expf(sv[tj] - mn); sum += p[tj]; }
#pragma unroll
      for (int mm = 8; mm >= 1; mm >>= 1) sum += __shfl_xor(sum, mm);
      l_run[r] = l_run[r] * alpha + sum;
      m_run[r] = mn;
#pragma unroll
      for (int td = 0; td < 4; ++td) oacc[td][r] *= alpha;
#pragma unroll
      for (int tj = 0; tj < 4; ++tj)
        ps[(wr + qq * 4 + r) * PAD + tj * 16 + c] = (f16)p[tj];
    }

    const half8 p0 = *(const half8*)&ps[(wr + c) * PAD + qq * 8];
    const half8 p1 = *(const half8*)&ps[(wr + c) * PAD + 32 + qq * 8];
#pragma unroll
    for (int td = 0; td < 4; ++td) {
      const half8 b0 = *(const half8*)&vts[(td * 16 + c) * PAD + qq * 8];
      const half8 b1 = *(const half8*)&vts[(td * 16 + c) * PAD + 32 + qq * 8];
      oacc[td] = __builtin_amdgcn_mfma_f32_16x16x32_f16(p0, b0, oacc[td], 0, 0, 0);
      oacc[td] = __builtin_amdgcn_mfma_f32_16x16x32_f16(p1, b1, oacc[td], 0, 0, 0);
    }
  }

#pragma unroll
  for (int td = 0; td < 4; ++td)
#pragma unroll
    for (int r = 0; r < 4; ++r) {
      const int ii = q0 + wr + qq * 4 + r;
      ao[((size_t)(b * Tseq + ii)) * Dm + hh * HDim + td * 16 + c] =
          (f16)(oacc[td][r] / l_run[r]);
    }
}

// ---------------------------------------------------------------- global row i = T-1 (split-j)
__global__ __launch_bounds__(256) void attn_row_part(const f16* __restrict__ qkv,
                                                     float* __restrict__ part) {
  const int bh = blockIdx.x, sp = blockIdx.y;
  const int b = bh >> 4, hh = bh & 15;
  const int tid = threadIdx.x;
  const size_t base = ((size_t)b * Tseq) * QS + hh * HDim;
  const int j0 = sp * (Tseq / NSPLIT);   // 128 keys per split
  __shared__ float qsh[64];
  __shared__ float ps[128];
  __shared__ float red[4];
  __shared__ float red2[4];
  __shared__ float oacc[4][64];
  if (tid < 64) qsh[tid] = (float)qkv[base + (size_t)(Tseq - 1) * QS + tid] * 0.125f;
  __syncthreads();
  float sv = -INFINITY;
  if (tid < 128) {
    const f16* kr = qkv + base + 1024 + (size_t)(j0 + tid) * QS;
    float a0 = 0.f;
#pragma unroll
    for (int d8 = 0; d8 < 8; ++d8) {
      const half8 kv = *(const half8*)(kr + d8 * 8);
#pragma unroll
      for (int e = 0; e < 8; ++e) a0 = fmaf((float)kv[e], qsh[d8 * 8 + e], a0);
    }
    sv = a0;  // row T-1: all j <= T-1 allowed
  }
  float mx = sv;
#pragma unroll
  for (int mm = 32; mm >= 1; mm >>= 1) mx = fmaxf(mx, __shfl_xor(mx, mm));
  if ((tid & 63) == 0) red[tid >> 6] = mx;
  __syncthreads();
  const float M = fmaxf(red[0], red[1]);  // waves 2,3 hold -inf
  float p = 0.f;
  if (tid < 128) { p = __expf(sv - M); ps[tid] = p; }
  float sum = p;
#pragma unroll
  for (int mm = 32; mm >= 1; mm >>= 1) sum += __shfl_xor(sum, mm);
  if ((tid & 63) == 0) red2[tid >> 6] = sum;
  __syncthreads();
  const float L = red2[0] + red2[1];
  const int d = tid & 63, pt = tid >> 6;
  const f16* vb = qkv + base + 2048 + d;
  float acc = 0.f;
  for (int j = pt * 32; j < pt * 32 + 32; ++j)
    acc = fmaf(ps[j], (float)vb[(size_t)(j0 + j) * QS], acc);
  oacc[pt][d] = acc;
  __syncthreads();
  if (tid < 64) {
    const float o = oacc[0][tid] + oacc[1][tid] + oacc[2][tid] + oacc[3][tid];
    float* dst = part + ((size_t)bh * NSPLIT + sp) * 66;
    dst[tid] = o;
    if (tid == 0) { dst[64] = M; dst[65] = L; }
  }
}

// Combine NSPLIT partials per (b,h) and write row T-1 of attnF.
__global__ __launch_bounds__(64) void attn_row_comb(const float* __restrict__ part,
                                                    f16* __restrict__ ao) {
  const int bh = blockIdx.x;
  const int b = bh >> 4, hh = bh & 15;
  const int tid = threadIdx.x;
  const float* pp = part + (size_t)bh * NSPLIT * 66;
  float M = -INFINITY;
#pragma unroll
  for (int s = 0; s < NSPLIT; ++s) M = fmaxf(M, pp[s * 66 + 64]);
  float L = 0.f, o = 0.f;
#pragma unroll
  for (int s = 0; s < NSPLIT; ++s) {
    const float wgt = __expf(pp[s * 66 + 64] - M);
    L += pp[s * 66 + 65] * wgt;
    o += pp[s * 66 + tid] * wgt;
  }
  ao[((size_t)(b * Tseq + Tseq - 1)) * Dm + hh * HDim + tid] = (f16)(o / L);
}

// ---------------------------------------------------------------- launch
extern "C" void kernel_launch(void* const* d_in, const int* in_sizes, int n_in,
                              void* d_out, int out_size, void* d_ws, size_t ws_size,
                              hipStream_t stream) {
  (void)in_sizes; (void)n_in; (void)out_size; (void)ws_size;
  const float* x    = (const float*)d_in[0];
  const float* ln1g = (const float*)d_in[1];
  const float* ln1b = (const float*)d_in[2];
  const float* ln2g = (const float*)d_in[3];
  const float* ln2b = (const float*)d_in[4];
  const float* Wq   = (const float*)d_in[5];
  const float* Wk   = (const float*)d_in[6];
  const float* Wv   = (const float*)d_in[7];
  const float* Wo   = (const float*)d_in[8];
  const float* bo   = (const float*)d_in[9];
  const float* W1   = (const float*)d_in[10];
  const float* b1   = (const float*)d_in[11];
  const float* W2   = (const float*)d_in[12];
  const float* b2   = (const float*)d_in[13];
  float* out = (float*)d_out;

  char* w0 = (char*)d_ws;
  size_t off = 0;
  auto take = [&](size_t bytes) -> char* {
    char* p = w0 + off;
    off += (bytes + 255) & ~(size_t)255;
    return p;
  };
  f16*   WqkvT = (f16*)take((size_t)3 * Dm * Dm * 2);  // Wq^T | Wk^T | Wv^T stacked
  f16*   WoT   = (f16*)take((size_t)Dm * Dm * 2);
  f16*   W1T   = (f16*)take((size_t)Dm * 4 * Dm * 2);
  f16*   W2T   = (f16*)take((size_t)Dm * 4 * Dm * 2);
  f16*   hF    = (f16*)take((size_t)Mrows * Dm * 2);
  f16*   qkvh  = (f16*)take((size_t)Mrows * QS * 2);   // 24 MiB
  f16*   attnF = (f16*)take((size_t)Mrows * Dm * 2);   // 8 MiB, contiguous after qkvh
  float* x1    = (float*)take((size_t)Mrows * Dm * 4);
  f16*   h2F   = (f16*)take((size_t)Mrows * Dm * 2);
  f16*   pbuf  = (f16*)take((size_t)4 * Mrows * Dm * 2);  // split-K f16 partials (32 MB)
  float* rowp  = (float*)take((size_t)32 * NSPLIT * 66 * 4);  // global-row partials
  int*   cnt   = (int*)take((size_t)256 * 4);             // W2 tile-finish counters
  f16*   ffn1F = qkvh;  // 4096x4096 f16 = 32 MiB == qkvh(24) + attnF(8) span

  const dim3 blk(256);
  hipMemsetAsync(cnt, 0, 256 * 4, stream);
  transp_qkv<<<dim3(Dm / 32, Dm / 32, 3), blk, 0, stream>>>(Wq, Wk, Wv, WqkvT);
  transp_f16<<<dim3(Dm / 32, Dm / 32), blk, 0, stream>>>(Wo, WoT, Dm, Dm);
  transp_f16<<<dim3(4 * Dm / 32, Dm / 32), blk, 0, stream>>>(W1, W1T, Dm, 4 * Dm);
  transp_f16<<<dim3(Dm / 32, 4 * Dm / 32), blk, 0, stream>>>(W2, W2T, 4 * Dm, Dm);

  ln_f16<<<Mrows, blk, 0, stream>>>(x, ln1g, ln1b, hF);

  // fused QKV: (4096x1024)@(1024x3072) -> qkvh (stride 3072); 768 blocks, BK=64
  gemm_f16<3, 0><<<dim3(QS / 128, Mrows / 128), blk, 0, stream>>>(
      hF, WqkvT, Mrows, QS, Dm, Dm, nullptr, qkvh, nullptr, nullptr, nullptr);

  attn_row_part<<<dim3(2 * NHd, NSPLIT), blk, 0, stream>>>(qkvh, rowp);
  attn_win<<<dim3(Tseq / 64, 2 * NHd), blk, 0, stream>>>(qkvh, attnF);
  attn_row_comb<<<dim3(2 * NHd), dim3(64), 0, stream>>>(rowp, attnF);

  // Wo: split-K2 f16 partials, flat grid with z in low bits (512 blocks)
  gemm_f16<5, 1><<<dim3(512), blk, 0, stream>>>(
      attnF, WoT, Mrows, Dm, Dm, Dm / 2, nullptr, pbuf, nullptr, nullptr, nullptr);
  reduce_ln<2><<<Mrows, blk, 0, stream>>>(pbuf, x, bo, ln2g, ln2b, x1, h2F);

  // FFN1: N=4096, 1024 blocks, fast-GELU epilogue
  gemm_f16<2, 0><<<dim3(4 * Dm / 128, Mrows / 128), blk, 0, stream>>>(
      h2F, W1T, Mrows, 4 * Dm, Dm, Dm, b1, ffn1F, nullptr, nullptr, nullptr);

  // W2: split-K4, flat grid (1024 blocks), fused last-finisher reduction -> out
  gemm_f16<6, 2><<<dim3(1024), blk, 0, stream>>>(
      ffn1F, W2T, Mrows, Dm, 4 * Dm, Dm, b2, pbuf, x1, out, cnt);
}

// Round 10
// 345.613 us; speedup vs baseline: 1.7757x; 1.7757x over previous
//
#include <hip/hip_runtime.h>
#include <cmath>

#define Tseq 2048
#define Dm   1024
#define NHd  16
#define HDim 64
#define Mrows 4096   // B*T = 2*2048
#define QS   3072    // packed QKV row stride (f16 elems)
#define PAD  72      // LDS row stride (f16) for attention tiles
#define NSPLIT 16    // j-splits for the global row (i = T-1)

typedef _Float16 f16;
typedef _Float16 half8 __attribute__((ext_vector_type(8)));
typedef _Float16 half4 __attribute__((ext_vector_type(4)));
typedef float    floatx4 __attribute__((ext_vector_type(4)));

#define ASYNC_COPY16(g, l)                                                       \
  __builtin_amdgcn_global_load_lds((const __attribute__((address_space(1))) void*)(g), \
                                   (__attribute__((address_space(3))) void*)(l), 16, 0, 0)

// tanh-form GELU, one __expf. |err vs exact erf-GELU| <= ~3e-4.
__device__ __forceinline__ float gelu_f(float v) {
  const float u = 0.7978845608028654f * (v + 0.044715f * v * v * v);
  const float e = __expf(2.0f * u);
  return 0.5f * v * (2.0f - 2.0f / (e + 1.0f));
}

// ---------------------------------------------------------------- transpose + cast
__global__ __launch_bounds__(256) void transp_f16(const float* __restrict__ W,
                                                  f16* __restrict__ Wt, int K, int N) {
  __shared__ float tile[32][33];
  const int n0 = blockIdx.x * 32, k0 = blockIdx.y * 32;
  const int tx = threadIdx.x & 31, ty = threadIdx.x >> 5;
#pragma unroll
  for (int i = 0; i < 32; i += 8)
    tile[ty + i][tx] = W[(size_t)(k0 + ty + i) * N + n0 + tx];
  __syncthreads();
#pragma unroll
  for (int i = 0; i < 32; i += 8)
    Wt[(size_t)(n0 + ty + i) * K + k0 + tx] = (f16)tile[tx][ty + i];
}

// Q/K/V transposes in one launch (blockIdx.z selects the weight)
__global__ __launch_bounds__(256) void transp_qkv(const float* __restrict__ Wq,
                                                  const float* __restrict__ Wk,
                                                  const float* __restrict__ Wv,
                                                  f16* __restrict__ Wt) {
  __shared__ float tile[32][33];
  const float* W = (blockIdx.z == 0) ? Wq : (blockIdx.z == 1) ? Wk : Wv;
  f16* dst = Wt + (size_t)blockIdx.z * Dm * Dm;
  const int n0 = blockIdx.x * 32, k0 = blockIdx.y * 32;
  const int tx = threadIdx.x & 31, ty = threadIdx.x >> 5;
#pragma unroll
  for (int i = 0; i < 32; i += 8)
    tile[ty + i][tx] = W[(size_t)(k0 + ty + i) * Dm + n0 + tx];
  __syncthreads();
#pragma unroll
  for (int i = 0; i < 32; i += 8)
    dst[(size_t)(n0 + ty + i) * Dm + k0 + tx] = (f16)tile[tx][ty + i];
}

// ---------------------------------------------------------------- layernorm -> f16
__global__ __launch_bounds__(256) void ln_f16(const float* __restrict__ x,
                                              const float* __restrict__ g,
                                              const float* __restrict__ bb,
                                              f16* __restrict__ out) {
  const int row = blockIdx.x, t = threadIdx.x;
  const float4 v = ((const float4*)(x + (size_t)row * Dm))[t];
  float s  = v.x + v.y + v.z + v.w;
  float ss = v.x * v.x + v.y * v.y + v.z * v.z + v.w * v.w;
#pragma unroll
  for (int m = 32; m >= 1; m >>= 1) { s += __shfl_xor(s, m); ss += __shfl_xor(ss, m); }
  __shared__ float red[8];
  if ((t & 63) == 0) { red[t >> 6] = s; red[4 + (t >> 6)] = ss; }
  __syncthreads();
  const float S  = red[0] + red[1] + red[2] + red[3];
  const float SS = red[4] + red[5] + red[6] + red[7];
  const float mean = S * (1.0f / Dm);
  const float inv  = rsqrtf(SS * (1.0f / Dm) - mean * mean + 1e-5f);
  const float4 gg = ((const float4*)g)[t];
  const float4 bv = ((const float4*)bb)[t];
  half4 o;
  o.x = (f16)(((v.x - mean) * inv) * gg.x + bv.x);
  o.y = (f16)(((v.y - mean) * inv) * gg.y + bv.y);
  o.z = (f16)(((v.z - mean) * inv) * gg.z + bv.z);
  o.w = (f16)(((v.w - mean) * inv) * gg.w + bv.w);
  *((half4*)(out + (size_t)row * Dm) + t) = o;
}

// ---------------------------------------------------------------- split-K reduce (+ fused LN)
template <int NS>
__global__ __launch_bounds__(256) void reduce_ln(const f16* __restrict__ P,
                                                 const float* __restrict__ resid,
                                                 const float* __restrict__ bias,
                                                 const float* __restrict__ g,
                                                 const float* __restrict__ bb,
                                                 float* __restrict__ x1,
                                                 f16* __restrict__ h) {
  const int row = blockIdx.x, t = threadIdx.x;
  const size_t idx = (size_t)row * (Dm / 4) + t;
  const float4 r = ((const float4*)resid)[idx];
  const float4 b = ((const float4*)bias)[t];
  float4 o; o.x = r.x + b.x; o.y = r.y + b.y; o.z = r.z + b.z; o.w = r.w + b.w;
#pragma unroll
  for (int z = 0; z < NS; ++z) {
    const half4 p = ((const half4*)(P + (size_t)z * Mrows * Dm))[idx];
    o.x += (float)p[0]; o.y += (float)p[1]; o.z += (float)p[2]; o.w += (float)p[3];
  }
  ((float4*)x1)[idx] = o;
  float s  = o.x + o.y + o.z + o.w;
  float ss = o.x * o.x + o.y * o.y + o.z * o.z + o.w * o.w;
#pragma unroll
  for (int m = 32; m >= 1; m >>= 1) { s += __shfl_xor(s, m); ss += __shfl_xor(ss, m); }
  __shared__ float red[8];
  if ((t & 63) == 0) { red[t >> 6] = s; red[4 + (t >> 6)] = ss; }
  __syncthreads();
  const float S  = red[0] + red[1] + red[2] + red[3];
  const float SS = red[4] + red[5] + red[6] + red[7];
  const float mean = S * (1.0f / Dm);
  const float inv  = rsqrtf(SS * (1.0f / Dm) - mean * mean + 1e-5f);
  const float4 gg = ((const float4*)g)[t];
  const float4 bv = ((const float4*)bb)[t];
  half4 oh;
  oh[0] = (f16)(((o.x - mean) * inv) * gg.x + bv.x);
  oh[1] = (f16)(((o.y - mean) * inv) * gg.y + bv.y);
  oh[2] = (f16)(((o.z - mean) * inv) * gg.z + bv.z);
  oh[3] = (f16)(((o.w - mean) * inv) * gg.w + bv.w);
  ((half4*)h)[idx] = oh;
}

// plain split-K reduce: out = resid + bias + sum_z P[z]
template <int NS>
__global__ __launch_bounds__(256) void reduceK(const f16* __restrict__ P,
                                               const float* __restrict__ resid,
                                               const float* __restrict__ bias,
                                               float* __restrict__ out) {
  const int t = blockIdx.x * 256 + threadIdx.x;
  const int col4 = t & (Dm / 4 - 1);
  const float4 r = ((const float4*)resid)[t];
  const float4 b = ((const float4*)bias)[col4];
  float4 o; o.x = r.x + b.x; o.y = r.y + b.y; o.z = r.z + b.z; o.w = r.w + b.w;
#pragma unroll
  for (int z = 0; z < NS; ++z) {
    const half4 p = ((const half4*)(P + (size_t)z * Mrows * Dm))[t];
    o.x += (float)p[0]; o.y += (float)p[1]; o.z += (float)p[2]; o.w += (float)p[3];
  }
  ((float4*)out)[t] = o;
}

// ---------------------------------------------------------------- GEMM 128x128, BK=64 (f16 MFMA)
// EPI 2: gelu(C+bias)->f16.  EPI 3: C->f16.
// EPI 5: f16 partial slab (split-K). Flat grid, z in low bits: round-robin block->XCD
// assignment gives each XCD one K-chunk's A-slab (streamed once) + L2-resident B slabs.
// Verified: FETCH 135 MB -> 62 MB (R9). NO fences/atomics here — kernel boundary orders.
template <int EPI, int LNZ>
__global__ __launch_bounds__(256, 4) void gemm_f16(const f16* __restrict__ A,
                                                   const f16* __restrict__ Bt,
                                                   int M, int N, int K, int kLen,
                                                   const float* __restrict__ bias,
                                                   f16* __restrict__ Ch) {
  constexpr int NZ = 1 << LNZ;
  __shared__ f16 As[128 * 64];   // 16 KB
  __shared__ f16 Bs[128 * 64];   // 16 KB
  const int tid = threadIdx.x;
  int bx, by, bz;
  if (EPI == 5) {
    const int lin = blockIdx.x;
    bz = lin & (NZ - 1);
    bx = (lin >> LNZ) & 7;        // N/128 == 8 for these GEMMs
    by = lin >> (LNZ + 3);
  } else {
    bx = blockIdx.x; by = blockIdx.y; bz = 0;
  }
  const int m0 = by * 128, n0 = bx * 128;
  const int kOff = bz * kLen;
  const int w = tid >> 6, l = tid & 63;
  const int wr = (w >> 1) * 64, wc = (w & 1) * 64;
  const int c = l & 15, qq = l >> 4;
  const int cx = c & 7;            // swizzle key for fragment reads
  const int srow = tid >> 3;       // 0..31 (staging row within 32-row group)
  const int scol = ((tid & 7) ^ (srow & 7)) * 8;  // swizzled global col (f16)

  floatx4 acc[4][4] = {};

  const f16* Ab = A + (size_t)(m0 + srow) * K + kOff + scol;
  const f16* Bb = Bt + (size_t)(n0 + srow) * K + kOff + scol;

  for (int k0 = 0; k0 < kLen; k0 += 64) {
    __syncthreads();
#pragma unroll
    for (int i = 0; i < 4; ++i) {
      ASYNC_COPY16(Ab + k0 + (size_t)(i * 32) * K, As + i * 2048 + w * 512);
      ASYNC_COPY16(Bb + k0 + (size_t)(i * 32) * K, Bs + i * 2048 + w * 512);
    }
    __syncthreads();
    half8 af[4][2], bfr[4][2];
#pragma unroll
    for (int t = 0; t < 4; ++t) {
      const int ra = (wr + t * 16 + c) * 64;
      af[t][0] = *(const half8*)&As[ra + ((qq ^ cx) * 8)];
      af[t][1] = *(const half8*)&As[ra + (((4 + qq) ^ cx) * 8)];
      const int rb = (wc + t * 16 + c) * 64;
      bfr[t][0] = *(const half8*)&Bs[rb + ((qq ^ cx) * 8)];
      bfr[t][1] = *(const half8*)&Bs[rb + (((4 + qq) ^ cx) * 8)];
    }
#pragma unroll
    for (int ti = 0; ti < 4; ++ti)
#pragma unroll
      for (int tj = 0; tj < 4; ++tj) {
        acc[ti][tj] = __builtin_amdgcn_mfma_f32_16x16x32_f16(af[ti][0], bfr[tj][0], acc[ti][tj], 0, 0, 0);
        acc[ti][tj] = __builtin_amdgcn_mfma_f32_16x16x32_f16(af[ti][1], bfr[tj][1], acc[ti][tj], 0, 0, 0);
      }
  }

  f16* Cw = (EPI == 5) ? (Ch + (size_t)bz * M * N) : Ch;
#pragma unroll
  for (int ti = 0; ti < 4; ++ti)
#pragma unroll
    for (int tj = 0; tj < 4; ++tj)
#pragma unroll
      for (int r = 0; r < 4; ++r) {
        const int row = m0 + wr + ti * 16 + qq * 4 + r;
        const int col = n0 + wc + tj * 16 + c;
        const size_t idx = (size_t)row * N + col;
        float v = acc[ti][tj][r];
        if (EPI == 2) {
          Cw[idx] = (f16)gelu_f(v + bias[col]);
        } else {
          Cw[idx] = (f16)v;
        }
      }
}

// ---------------------------------------------------------------- windowed attention (MFMA)
__global__ __launch_bounds__(256, 4) void attn_win(const f16* __restrict__ qkv,
                                                   f16* __restrict__ ao) {
  __shared__ f16 qs[64 * PAD];   // [i][d]
  __shared__ f16 ks[64 * PAD];   // [j][d]
  __shared__ f16 vts[64 * PAD];  // [d][j]  (transposed)
  __shared__ f16 ps[64 * PAD];   // [i][j]  wave-private row slices
  const int qt = blockIdx.x;
  const int b = blockIdx.y >> 4, hh = blockIdx.y & 15;
  const int q0 = qt * 64;
  const int tid = threadIdx.x, w = tid >> 6, l = tid & 63;
  const int c = l & 15, qq = l >> 4;
  const int wr = w * 16;
  const size_t base = ((size_t)b * Tseq) * QS + hh * HDim;
  const int rr = tid >> 2, ss = (tid & 3) * 16;

  {
    const f16* src = qkv + base + (size_t)(q0 + rr) * QS + ss;
    *(uint4*)&qs[rr * PAD + ss]     = *(const uint4*)src;
    *(uint4*)&qs[rr * PAD + ss + 8] = *(const uint4*)(src + 8);
  }

  float m_run[4], l_run[4];
  floatx4 oacc[4];
#pragma unroll
  for (int r = 0; r < 4; ++r) { m_run[r] = -INFINITY; l_run[r] = 0.f; }
#pragma unroll
  for (int td = 0; td < 4; ++td) oacc[td] = (floatx4){0.f, 0.f, 0.f, 0.f};

  int chunks[4]; int nch = 0;
  if (qt > 2) chunks[nch++] = 0;
  for (int ch = (qt - 2 > 0 ? qt - 2 : 0); ch <= qt; ++ch) chunks[nch++] = ch;

  for (int ci = 0; ci < nch; ++ci) {
    const int j0 = chunks[ci] * 64;
    __syncthreads();
    {
      const f16* srck = qkv + base + 1024 + (size_t)(j0 + rr) * QS + ss;
      *(uint4*)&ks[rr * PAD + ss]     = *(const uint4*)srck;
      *(uint4*)&ks[rr * PAD + ss + 8] = *(const uint4*)(srck + 8);
      const f16* srcv = qkv + base + 2048 + (size_t)(j0 + rr) * QS + ss;
      uint4 va0 = *(const uint4*)srcv;
      uint4 va1 = *(const uint4*)(srcv + 8);
      const f16* e0 = (const f16*)&va0;
      const f16* e1 = (const f16*)&va1;
#pragma unroll
      for (int i = 0; i < 8; ++i) vts[(ss + i) * PAD + rr] = e0[i];
#pragma unroll
      for (int i = 0; i < 8; ++i) vts[(ss + 8 + i) * PAD + rr] = e1[i];
    }
    __syncthreads();

    const half8 a0 = *(const half8*)&qs[(wr + c) * PAD + qq * 8];
    const half8 a1 = *(const half8*)&qs[(wr + c) * PAD + 32 + qq * 8];
    floatx4 sacc[4];
#pragma unroll
    for (int tj = 0; tj < 4; ++tj) {
      const half8 b0 = *(const half8*)&ks[(tj * 16 + c) * PAD + qq * 8];
      const half8 b1 = *(const half8*)&ks[(tj * 16 + c) * PAD + 32 + qq * 8];
      floatx4 s4 = {0.f, 0.f, 0.f, 0.f};
      s4 = __builtin_amdgcn_mfma_f32_16x16x32_f16(a0, b0, s4, 0, 0, 0);
      s4 = __builtin_amdgcn_mfma_f32_16x16x32_f16(a1, b1, s4, 0, 0, 0);
      sacc[tj] = s4;
    }

#pragma unroll
    for (int r = 0; r < 4; ++r) {
      const int ii = q0 + wr + qq * 4 + r;
      float sv[4];
      float mx = -INFINITY;
#pragma unroll
      for (int tj = 0; tj < 4; ++tj) {
        const int jj = j0 + tj * 16 + c;
        const bool allowed = (jj <= ii) && ((ii - jj) <= 128 || jj == 0);
        sv[tj] = allowed ? sacc[tj][r] * 0.125f : -INFINITY;
        mx = fmaxf(mx, sv[tj]);
      }
#pragma unroll
      for (int mm = 8; mm >= 1; mm >>= 1) mx = fmaxf(mx, __shfl_xor(mx, mm));
      const float mn = fmaxf(m_run[r], mx);
      const float alpha = (mn == -INFINITY) ? 1.f : __expf(m_run[r] - mn);
      float sum = 0.f;
      float p[4];
#pragma unroll
      for (int tj = 0; tj < 4; ++tj) { p[tj] = __expf(sv[tj] - mn); sum += p[tj]; }
#pragma unroll
      for (int mm = 8; mm >= 1; mm >>= 1) sum += __shfl_xor(sum, mm);
      l_run[r] = l_run[r] * alpha + sum;
      m_run[r] = mn;
#pragma unroll
      for (int td = 0; td < 4; ++td) oacc[td][r] *= alpha;
#pragma unroll
      for (int tj = 0; tj < 4; ++tj)
        ps[(wr + qq * 4 + r) * PAD + tj * 16 + c] = (f16)p[tj];
    }

    const half8 p0 = *(const half8*)&ps[(wr + c) * PAD + qq * 8];
    const half8 p1 = *(const half8*)&ps[(wr + c) * PAD + 32 + qq * 8];
#pragma unroll
    for (int td = 0; td < 4; ++td) {
      const half8 b0 = *(const half8*)&vts[(td * 16 + c) * PAD + qq * 8];
      const half8 b1 = *(const half8*)&vts[(td * 16 + c) * PAD + 32 + qq * 8];
      oacc[td] = __builtin_amdgcn_mfma_f32_16x16x32_f16(p0, b0, oacc[td], 0, 0, 0);
      oacc[td] = __builtin_amdgcn_mfma_f32_16x16x32_f16(p1, b1, oacc[td], 0, 0, 0);
    }
  }

#pragma unroll
  for (int td = 0; td < 4; ++td)
#pragma unroll
    for (int r = 0; r < 4; ++r) {
      const int ii = q0 + wr + qq * 4 + r;
      ao[((size_t)(b * Tseq + ii)) * Dm + hh * HDim + td * 16 + c] =
          (f16)(oacc[td][r] / l_run[r]);
    }
}

// ---------------------------------------------------------------- global row i = T-1 (split-j)
__global__ __launch_bounds__(256) void attn_row_part(const f16* __restrict__ qkv,
                                                     float* __restrict__ part) {
  const int bh = blockIdx.x, sp = blockIdx.y;
  const int b = bh >> 4, hh = bh & 15;
  const int tid = threadIdx.x;
  const size_t base = ((size_t)b * Tseq) * QS + hh * HDim;
  const int j0 = sp * (Tseq / NSPLIT);   // 128 keys per split
  __shared__ float qsh[64];
  __shared__ float ps[128];
  __shared__ float red[4];
  __shared__ float red2[4];
  __shared__ float oacc[4][64];
  if (tid < 64) qsh[tid] = (float)qkv[base + (size_t)(Tseq - 1) * QS + tid] * 0.125f;
  __syncthreads();
  float sv = -INFINITY;
  if (tid < 128) {
    const f16* kr = qkv + base + 1024 + (size_t)(j0 + tid) * QS;
    float a0 = 0.f;
#pragma unroll
    for (int d8 = 0; d8 < 8; ++d8) {
      const half8 kv = *(const half8*)(kr + d8 * 8);
#pragma unroll
      for (int e = 0; e < 8; ++e) a0 = fmaf((float)kv[e], qsh[d8 * 8 + e], a0);
    }
    sv = a0;  // row T-1: all j <= T-1 allowed
  }
  float mx = sv;
#pragma unroll
  for (int mm = 32; mm >= 1; mm >>= 1) mx = fmaxf(mx, __shfl_xor(mx, mm));
  if ((tid & 63) == 0) red[tid >> 6] = mx;
  __syncthreads();
  const float M = fmaxf(red[0], red[1]);  // waves 2,3 hold -inf
  float p = 0.f;
  if (tid < 128) { p = __expf(sv - M); ps[tid] = p; }
  float sum = p;
#pragma unroll
  for (int mm = 32; mm >= 1; mm >>= 1) sum += __shfl_xor(sum, mm);
  if ((tid & 63) == 0) red2[tid >> 6] = sum;
  __syncthreads();
  const float L = red2[0] + red2[1];
  const int d = tid & 63, pt = tid >> 6;
  const f16* vb = qkv + base + 2048 + d;
  float acc = 0.f;
  for (int j = pt * 32; j < pt * 32 + 32; ++j)
    acc = fmaf(ps[j], (float)vb[(size_t)(j0 + j) * QS], acc);
  oacc[pt][d] = acc;
  __syncthreads();
  if (tid < 64) {
    const float o = oacc[0][tid] + oacc[1][tid] + oacc[2][tid] + oacc[3][tid];
    float* dst = part + ((size_t)bh * NSPLIT + sp) * 66;
    dst[tid] = o;
    if (tid == 0) { dst[64] = M; dst[65] = L; }
  }
}

// Combine NSPLIT partials per (b,h) and write row T-1 of attnF.
__global__ __launch_bounds__(64) void attn_row_comb(const float* __restrict__ part,
                                                    f16* __restrict__ ao) {
  const int bh = blockIdx.x;
  const int b = bh >> 4, hh = bh & 15;
  const int tid = threadIdx.x;
  const float* pp = part + (size_t)bh * NSPLIT * 66;
  float M = -INFINITY;
#pragma unroll
  for (int s = 0; s < NSPLIT; ++s) M = fmaxf(M, pp[s * 66 + 64]);
  float L = 0.f, o = 0.f;
#pragma unroll
  for (int s = 0; s < NSPLIT; ++s) {
    const float wgt = __expf(pp[s * 66 + 64] - M);
    L += pp[s * 66 + 65] * wgt;
    o += pp[s * 66 + tid] * wgt;
  }
  ao[((size_t)(b * Tseq + Tseq - 1)) * Dm + hh * HDim + tid] = (f16)(o / L);
}

// ---------------------------------------------------------------- launch
extern "C" void kernel_launch(void* const* d_in, const int* in_sizes, int n_in,
                              void* d_out, int out_size, void* d_ws, size_t ws_size,
                              hipStream_t stream) {
  (void)in_sizes; (void)n_in; (void)out_size; (void)ws_size;
  const float* x    = (const float*)d_in[0];
  const float* ln1g = (const float*)d_in[1];
  const float* ln1b = (const float*)d_in[2];
  const float* ln2g = (const float*)d_in[3];
  const float* ln2b = (const float*)d_in[4];
  const float* Wq   = (const float*)d_in[5];
  const float* Wk   = (const float*)d_in[6];
  const float* Wv   = (const float*)d_in[7];
  const float* Wo   = (const float*)d_in[8];
  const float* bo   = (const float*)d_in[9];
  const float* W1   = (const float*)d_in[10];
  const float* b1   = (const float*)d_in[11];
  const float* W2   = (const float*)d_in[12];
  const float* b2   = (const float*)d_in[13];
  float* out = (float*)d_out;

  char* w0 = (char*)d_ws;
  size_t off = 0;
  auto take = [&](size_t bytes) -> char* {
    char* p = w0 + off;
    off += (bytes + 255) & ~(size_t)255;
    return p;
  };
  f16*   WqkvT = (f16*)take((size_t)3 * Dm * Dm * 2);  // Wq^T | Wk^T | Wv^T stacked
  f16*   WoT   = (f16*)take((size_t)Dm * Dm * 2);
  f16*   W1T   = (f16*)take((size_t)Dm * 4 * Dm * 2);
  f16*   W2T   = (f16*)take((size_t)Dm * 4 * Dm * 2);
  f16*   hF    = (f16*)take((size_t)Mrows * Dm * 2);
  f16*   qkvh  = (f16*)take((size_t)Mrows * QS * 2);   // 24 MiB
  f16*   attnF = (f16*)take((size_t)Mrows * Dm * 2);   // 8 MiB, contiguous after qkvh
  float* x1    = (float*)take((size_t)Mrows * Dm * 4);
  f16*   h2F   = (f16*)take((size_t)Mrows * Dm * 2);
  f16*   pbuf  = (f16*)take((size_t)4 * Mrows * Dm * 2);  // split-K f16 partials (32 MB)
  float* rowp  = (float*)take((size_t)32 * NSPLIT * 66 * 4);  // global-row partials
  f16*   ffn1F = qkvh;  // 4096x4096 f16 = 32 MiB == qkvh(24) + attnF(8) span

  const dim3 blk(256);
  transp_qkv<<<dim3(Dm / 32, Dm / 32, 3), blk, 0, stream>>>(Wq, Wk, Wv, WqkvT);
  transp_f16<<<dim3(Dm / 32, Dm / 32), blk, 0, stream>>>(Wo, WoT, Dm, Dm);
  transp_f16<<<dim3(4 * Dm / 32, Dm / 32), blk, 0, stream>>>(W1, W1T, Dm, 4 * Dm);
  transp_f16<<<dim3(Dm / 32, 4 * Dm / 32), blk, 0, stream>>>(W2, W2T, 4 * Dm, Dm);

  ln_f16<<<Mrows, blk, 0, stream>>>(x, ln1g, ln1b, hF);

  // fused QKV: (4096x1024)@(1024x3072) -> qkvh (stride 3072); 768 blocks, BK=64
  gemm_f16<3, 0><<<dim3(QS / 128, Mrows / 128), blk, 0, stream>>>(
      hF, WqkvT, Mrows, QS, Dm, Dm, nullptr, qkvh);

  attn_row_part<<<dim3(2 * NHd, NSPLIT), blk, 0, stream>>>(qkvh, rowp);
  attn_win<<<dim3(Tseq / 64, 2 * NHd), blk, 0, stream>>>(qkvh, attnF);
  attn_row_comb<<<dim3(2 * NHd), dim3(64), 0, stream>>>(rowp, attnF);

  // Wo: split-K2 f16 partials, flat grid with z in low bits (512 blocks)
  gemm_f16<5, 1><<<dim3(512), blk, 0, stream>>>(
      attnF, WoT, Mrows, Dm, Dm, Dm / 2, nullptr, pbuf);
  reduce_ln<2><<<Mrows, blk, 0, stream>>>(pbuf, x, bo, ln2g, ln2b, x1, h2F);

  // FFN1: N=4096, 1024 blocks, fast-GELU epilogue
  gemm_f16<2, 0><<<dim3(4 * Dm / 128, Mrows / 128), blk, 0, stream>>>(
      h2F, W1T, Mrows, 4 * Dm, Dm, Dm, b1, ffn1F);

  // W2: split-K4 f16 partials, flat grid (1024 blocks), then out = x1 + b2 + sum(P)
  gemm_f16<5, 2><<<dim3(1024), blk, 0, stream>>>(
      ffn1F, W2T, Mrows, Dm, 4 * Dm, Dm, nullptr, pbuf);
  reduceK<4><<<Mrows * Dm / 1024, blk, 0, stream>>>(pbuf, x1, b2, out);
}